// Round 5
// baseline (1271.730 us; speedup 1.0000x reference)
//
#include <hip/hip_runtime.h>
#include <hip/hip_bf16.h>

typedef __attribute__((ext_vector_type(8))) short bf16x8;   // 8 bf16 = 4 VGPRs (MFMA A/B frag)
typedef __attribute__((ext_vector_type(4))) float f32x4;    // MFMA C/D frag
typedef __attribute__((ext_vector_type(4))) _Float16 f16x4; // 8 B gather unit
typedef unsigned short ushort_t;

#define NN   100000
#define NE   3200000
#define IND  512
#define HIDD 256
#define OUTD 64

#define NBKT 98            // buckets of 1024 nodes: ceil(100000/1024)=98
#define P1E  2048          // edges per phase-1 block

// bf16 helpers (RTNE, manual bit math — no NaN inputs in this problem)
__device__ __forceinline__ ushort_t f2bf(float a) {
    unsigned u = __float_as_uint(a);
    unsigned r = (u + 0x7FFFu + ((u >> 16) & 1u)) >> 16;
    return (ushort_t)r;
}
__device__ __forceinline__ float bf2f(ushort_t b) {
    return __uint_as_float(((unsigned)b) << 16);
}

union U8 { ushort_t us[8]; unsigned u32[4]; uint4 v; };

// async global->LDS, 16 B per lane (linear LDS dest = base + lane*16)
#define GLOAD_LDS16(gp, lp) \
    __builtin_amdgcn_global_load_lds( \
        (const __attribute__((address_space(1))) void*)(const void*)(gp), \
        (__attribute__((address_space(3))) void*)(void*)(lp), 16, 0, 0)

// register hi/lo split of 8 f32 -> two bf16x8 (hi = truncate, lo = truncate of
// the exact residual; dropped lo*lo term <= 2^-17 rel — invisible vs fp16 out)
__device__ __forceinline__ void split8(float4 v0, float4 v1, bf16x8& aH, bf16x8& aL) {
    float vv[8] = {v0.x, v0.y, v0.z, v0.w, v1.x, v1.y, v1.z, v1.w};
    U8 H, L;
    #pragma unroll
    for (int j = 0; j < 4; ++j) {
        unsigned u0 = __float_as_uint(vv[2 * j]);
        unsigned u1 = __float_as_uint(vv[2 * j + 1]);
        H.u32[j] = __builtin_amdgcn_perm(u1, u0, 0x07060302u);
        float r0 = vv[2 * j]     - __uint_as_float(u0 & 0xFFFF0000u);
        float r1 = vv[2 * j + 1] - __uint_as_float(u1 & 0xFFFF0000u);
        L.u32[j] = __builtin_amdgcn_perm(__float_as_uint(r1),
                                         __float_as_uint(r0), 0x07060302u);
    }
    aH = *(const bf16x8*)&H.v;
    aL = *(const bf16x8*)&L.v;
}

// ------------------------------------------------- weight transpose + hi/lo split
__global__ void splitw_k(const float* __restrict__ in, ushort_t* __restrict__ thi,
                         ushort_t* __restrict__ tlo, int R, int C) {
    int i = blockIdx.x * 256 + threadIdx.x;
    if (i < R * C) {
        int r = i / C, c = i % C;
        float a = in[i];
        ushort_t h = f2bf(a);
        thi[(size_t)c * R + r] = h;
        tlo[(size_t)c * R + r] = f2bf(a - bf2f(h));
    }
}

// ------------------------------------------------- layer-1 GEMM: S1 = x @ W1 (fp16 out)
// m97-style: global_load_lds staging (no ds_writes), single LDS buffer, 2 barriers/k-step.
// A stays f32 in LDS; hi/lo split happens in registers after ds_read.
// Both LDS tiles XOR-swizzled on source AND read (rule 21) -> 2-way (free) bank pattern.
// 128x128 tile, wave=64x64 (acc[4][4]), 3 blocks/CU.
__global__ __launch_bounds__(256, 3) void gemm1_k(
    const float* __restrict__ A, const ushort_t* __restrict__ BtHi,
    const ushort_t* __restrict__ BtLo, _Float16* __restrict__ C)
{
    const int M = NN, N = HIDD, K = IND;
    __shared__ __align__(16) float    sA [128 * 32];   // 16 KiB, swizzled
    __shared__ __align__(16) ushort_t sBh[128 * 32];   // 8 KiB, swizzled
    __shared__ __align__(16) ushort_t sBl[128 * 32];   // 8 KiB

    const int tid  = threadIdx.x;
    const int wave = tid >> 6;
    const int lane = tid & 63;
    const int quad = lane >> 4;
    const int l15  = lane & 15;
    const int wr   = wave >> 1;          // 0..1 (row half)
    const int wc   = wave & 1;           // 0..1 (col half)
    const int n0   = blockIdx.x * 128;   // x-fast: both n-blocks of an m-panel adjacent
    const int m0   = blockIdx.y * 128;

    // ---- staging descriptors (k0-invariant). A: 128 rows x 32 f32, 16B-block
    // swizzle blk' = blk ^ ((r&3)<<1) ^ ((r>>2)&1) applied to the GLOBAL source.
    const float* aSrc[4];
    float*       aDst[4];
    #pragma unroll
    for (int it = 0; it < 4; ++it) {
        int f = it * 256 + tid;          // 16B block 0..1023
        int r = f >> 3;                  // 8 blocks per row
        int bp = (f & 7) ^ ((r & 3) << 1) ^ ((r >> 2) & 1);
        int gr = m0 + r; if (gr >= M) gr = M - 1;   // clamp; results row-guarded on store
        aSrc[it] = A + (size_t)gr * K + bp * 4;
        aDst[it] = &sA[f * 4];
    }
    // B: 128 rows (cols of C) x 32 bf16, block swizzle q' = q ^ ((r>>1)&3)
    const ushort_t* bhSrc[2]; const ushort_t* blSrc[2];
    ushort_t* bhDst[2]; ushort_t* blDst[2];
    #pragma unroll
    for (int it = 0; it < 2; ++it) {
        int f = it * 256 + tid;          // block 0..511
        int r = f >> 2;                  // 4 blocks per row
        int qp = (f & 3) ^ ((r >> 1) & 3);
        bhSrc[it] = BtHi + (size_t)(n0 + r) * K + qp * 8;
        blSrc[it] = BtLo + (size_t)(n0 + r) * K + qp * 8;
        bhDst[it] = &sBh[f * 8];
        blDst[it] = &sBl[f * 8];
    }

    // ---- fragment read offsets with the matching read-side swizzle
    int aOff[4][2];
    #pragma unroll
    for (int ms = 0; ms < 4; ++ms) {
        int rA = wr * 64 + ms * 16 + l15;
        int sw = ((rA & 3) << 1) ^ ((rA >> 2) & 1);
        int cb = quad << 1;
        aOff[ms][0] = rA * 32 + (((cb    ) ^ sw) << 2);
        aOff[ms][1] = rA * 32 + (((cb | 1) ^ sw) << 2);
    }
    int bOff[4];
    #pragma unroll
    for (int ns = 0; ns < 4; ++ns) {
        int rB = wc * 64 + ns * 16 + l15;
        bOff[ns] = rB * 32 + (quad ^ ((rB >> 1) & 3)) * 8;
    }

    f32x4 acc[4][4] = {};

    for (int k0 = 0; k0 < K; k0 += 32) {
        #pragma unroll
        for (int it = 0; it < 4; ++it) GLOAD_LDS16(aSrc[it] + k0, aDst[it]);
        #pragma unroll
        for (int it = 0; it < 2; ++it) {
            GLOAD_LDS16(bhSrc[it] + k0, bhDst[it]);
            GLOAD_LDS16(blSrc[it] + k0, blDst[it]);
        }
        __syncthreads();

        bf16x8 aH[4], aL[4];
        #pragma unroll
        for (int ms = 0; ms < 4; ++ms) {
            float4 v0 = *(const float4*)&sA[aOff[ms][0]];
            float4 v1 = *(const float4*)&sA[aOff[ms][1]];
            split8(v0, v1, aH[ms], aL[ms]);
        }

        #pragma unroll
        for (int ns = 0; ns < 4; ++ns) {
            bf16x8 bH = *(const bf16x8*)&sBh[bOff[ns]];
            bf16x8 bL = *(const bf16x8*)&sBl[bOff[ns]];
            #pragma unroll
            for (int ms = 0; ms < 4; ++ms) {
                acc[ms][ns] = __builtin_amdgcn_mfma_f32_16x16x32_bf16(aH[ms], bH, acc[ms][ns], 0, 0, 0);
                acc[ms][ns] = __builtin_amdgcn_mfma_f32_16x16x32_bf16(aL[ms], bH, acc[ms][ns], 0, 0, 0);
                acc[ms][ns] = __builtin_amdgcn_mfma_f32_16x16x32_bf16(aH[ms], bL, acc[ms][ns], 0, 0, 0);
            }
        }
        __syncthreads();
    }

    #pragma unroll
    for (int ms = 0; ms < 4; ++ms) {
        int row = m0 + wr * 64 + ms * 16 + quad * 4;
        #pragma unroll
        for (int ns = 0; ns < 4; ++ns) {
            int col = n0 + wc * 64 + ns * 16 + l15;
            #pragma unroll
            for (int r = 0; r < 4; ++r)
                if (row + r < M) C[(size_t)(row + r) * N + col] = (_Float16)acc[ms][ns][r];
        }
    }
}

// ---------------------------------------------------------------- CSR build (binned)
__global__ __launch_bounds__(256) void bhist_k(const int* __restrict__ dst,
                                               int* __restrict__ bucketHist) {
    __shared__ int h[NBKT];
    int t = threadIdx.x;
    if (t < NBKT) h[t] = 0;
    __syncthreads();
    #pragma unroll
    for (int j = 0; j < 4; ++j) {
        int e = blockIdx.x * 1024 + t + j * 256;
        if (e < NE) atomicAdd(&h[dst[e] >> 10], 1);
    }
    __syncthreads();
    if (t < NBKT && h[t]) atomicAdd(&bucketHist[t], h[t]);
}

__global__ __launch_bounds__(128) void bscan_k(const int* __restrict__ bucketHist,
                                               int* __restrict__ bucketStart,
                                               int* __restrict__ bucketCursor) {
    __shared__ int s[128];
    int t = threadIdx.x;
    int v = (t < NBKT) ? bucketHist[t] : 0;
    s[t] = v;
    for (int off = 1; off < 128; off <<= 1) {
        __syncthreads();
        int a = (t >= off) ? s[t - off] : 0;
        __syncthreads();
        s[t] += a;
    }
    __syncthreads();
    if (t < NBKT) { bucketStart[t] = s[t] - v; bucketCursor[t] = s[t] - v; }
    if (t == NBKT - 1) bucketStart[NBKT] = s[t];
}

__global__ __launch_bounds__(256) void phase1_k(
    const int* __restrict__ src, const int* __restrict__ dst,
    const float* __restrict__ w, int* __restrict__ bucketCursor,
    int2* __restrict__ binned)
{
    __shared__ int2 raw[P1E];
    __shared__ int2 ord[P1E];
    __shared__ ushort_t rbkt[P1E], obkt[P1E];
    __shared__ int hist[128], excl[128], cursor[128], gbase[128], stmp[128];

    int t = threadIdx.x;
    if (t < 128) hist[t] = 0;
    __syncthreads();

    int e0 = blockIdx.x * P1E;
    #pragma unroll
    for (int j = 0; j < P1E / 256; ++j) {
        int li = t + j * 256;
        int e = e0 + li;
        if (e < NE) {
            int d = dst[e];
            int b = d >> 10;
            raw[li] = make_int2(src[e] | ((d & 1023) << 17), __float_as_int(w[e]));
            rbkt[li] = (ushort_t)b;
            atomicAdd(&hist[b], 1);
        } else rbkt[li] = 0xFFFFu;
    }
    __syncthreads();
    int v = (t < 128) ? hist[t] : 0;
    if (t < 128) stmp[t] = v;
    for (int off = 1; off < 128; off <<= 1) {
        __syncthreads();
        int a = (t < 128 && t >= off) ? stmp[t - off] : 0;
        __syncthreads();
        if (t < 128) stmp[t] += a;
    }
    __syncthreads();
    if (t < 128) { excl[t] = stmp[t] - v; cursor[t] = stmp[t] - v; }
    if (t < NBKT) gbase[t] = atomicAdd(&bucketCursor[t], hist[t]);
    __syncthreads();
    #pragma unroll
    for (int j = 0; j < P1E / 256; ++j) {
        int li = t + j * 256;
        ushort_t b = rbkt[li];
        if (b != 0xFFFFu) {
            int p = atomicAdd(&cursor[b], 1);
            ord[p] = raw[li];
            obkt[p] = b;
        }
    }
    __syncthreads();
    int tot = excl[NBKT - 1] + hist[NBKT - 1];
    #pragma unroll
    for (int j = 0; j < P1E / 256; ++j) {
        int li = t + j * 256;
        if (li < tot) {
            int b = obkt[li];
            binned[(size_t)gbase[b] + (li - excl[b])] = ord[li];
        }
    }
}

__global__ __launch_bounds__(256) void phase2_k(
    const int* __restrict__ bucketStart, const int2* __restrict__ binned,
    int* __restrict__ rowptr, int2* __restrict__ esw)
{
    __shared__ int cnt[1024], ex[1024], cur[1024], wsum[256];
    int t = threadIdx.x, blk = blockIdx.x;
    int gb = bucketStart[blk], ge = bucketStart[blk + 1];
    #pragma unroll
    for (int j = 0; j < 4; ++j) cnt[t + j * 256] = 0;
    __syncthreads();
    for (int e = gb + t; e < ge; e += 256)
        atomicAdd(&cnt[(binned[e].x >> 17) & 1023], 1);
    __syncthreads();
    int b4 = t * 4;
    int l0 = cnt[b4], l1 = cnt[b4 + 1], l2 = cnt[b4 + 2], l3 = cnt[b4 + 3];
    int ls = l0 + l1 + l2 + l3;
    wsum[t] = ls;
    for (int off = 1; off < 256; off <<= 1) {
        __syncthreads();
        int a = (t >= off) ? wsum[t - off] : 0;
        __syncthreads();
        wsum[t] += a;
    }
    __syncthreads();
    int be = wsum[t] - ls;
    ex[b4] = be;            cur[b4] = be;
    ex[b4 + 1] = be + l0;     cur[b4 + 1] = be + l0;
    ex[b4 + 2] = be + l0 + l1;  cur[b4 + 2] = be + l0 + l1;
    ex[b4 + 3] = be + l0 + l1 + l2; cur[b4 + 3] = be + l0 + l1 + l2;
    __syncthreads();
    int n0 = blk << 10;
    #pragma unroll
    for (int j = 0; j < 4; ++j) {
        int i = b4 + j;
        if (n0 + i < NN) rowptr[n0 + i] = gb + ex[i];
    }
    if (blk == NBKT - 1 && t == 0) rowptr[NN] = NE;
    for (int e = gb + t; e < ge; e += 256) {
        int2 en = binned[e];
        int d = (en.x >> 17) & 1023;
        int p = atomicAdd(&cur[d], 1);
        esw[(size_t)gb + p] = make_int2(en.x & 0x1FFFF, en.y);
    }
}

// ---------------------------------------------------------------- fused SpMM1+ReLU+GEMM2
// Block = 32 nodes, 8 waves (512 thr). Phase 1: each wave owns 4 nodes and
// gathers them INTERLEAVED in one loop — 4 independent load streams per wave
// (x2 unroll => ~8-16 loads in flight) instead of R2's 1 stream; predicates
// are wave-uniform (same node across lanes) so exhausted rows cost ~nothing.
// Phase 2: wave w = (rt = w>>2, ct = w&3) computes S2 rows [rt*16,+16) x cols
// [ct*16,+16) via register hi/lo split + 3-MFMA; B-frags from the L2-resident
// 64 KB W2t tables. LDS 33 KB -> 4 blocks/CU.
__global__ __launch_bounds__(512) void spmm_relu_gemm2_k(
    const int* __restrict__ rowptr, const int2* __restrict__ esw,
    const _Float16* __restrict__ X, const ushort_t* __restrict__ BtHi,
    const ushort_t* __restrict__ BtLo, _Float16* __restrict__ S2)
{
    __shared__ __align__(16) float h[32][260];

    const int tid   = threadIdx.x;
    const int wave  = tid >> 6;      // 0..7
    const int lane  = tid & 63;
    const int quad  = lane >> 4;
    const int l15   = lane & 15;
    const int nbase = blockIdx.x * 32;
    const int nw    = nbase + wave * 4;

    // ---- phase 1: interleaved gather of the wave's 4 nodes
    int beg0 = rowptr[nw],     end0 = rowptr[nw + 1];
    int beg1 = rowptr[nw + 1], end1 = rowptr[nw + 2];
    int beg2 = rowptr[nw + 2], end2 = rowptr[nw + 3];
    int beg3 = rowptr[nw + 3], end3 = rowptr[nw + 4];
    int maxd = max(max(end0 - beg0, end1 - beg1), max(end2 - beg2, end3 - beg3));

    f32x4 a0 = {0.f,0.f,0.f,0.f}, a1 = a0, a2 = a0, a3 = a0;
    const _Float16* Xl = X + lane * 4;

    #pragma unroll 2
    for (int j = 0; j < maxd; ++j) {
        if (beg0 + j < end0) {
            int2 sw = esw[beg0 + j];
            float w = __int_as_float(sw.y);
            f16x4 v = *(const f16x4*)(Xl + (size_t)sw.x * HIDD);
            a0.x += (float)v[0] * w; a0.y += (float)v[1] * w;
            a0.z += (float)v[2] * w; a0.w += (float)v[3] * w;
        }
        if (beg1 + j < end1) {
            int2 sw = esw[beg1 + j];
            float w = __int_as_float(sw.y);
            f16x4 v = *(const f16x4*)(Xl + (size_t)sw.x * HIDD);
            a1.x += (float)v[0] * w; a1.y += (float)v[1] * w;
            a1.z += (float)v[2] * w; a1.w += (float)v[3] * w;
        }
        if (beg2 + j < end2) {
            int2 sw = esw[beg2 + j];
            float w = __int_as_float(sw.y);
            f16x4 v = *(const f16x4*)(Xl + (size_t)sw.x * HIDD);
            a2.x += (float)v[0] * w; a2.y += (float)v[1] * w;
            a2.z += (float)v[2] * w; a2.w += (float)v[3] * w;
        }
        if (beg3 + j < end3) {
            int2 sw = esw[beg3 + j];
            float w = __int_as_float(sw.y);
            f16x4 v = *(const f16x4*)(Xl + (size_t)sw.x * HIDD);
            a3.x += (float)v[0] * w; a3.y += (float)v[1] * w;
            a3.z += (float)v[2] * w; a3.w += (float)v[3] * w;
        }
    }
    {
        f32x4 r;
        r.x = fmaxf(a0.x, 0.f); r.y = fmaxf(a0.y, 0.f); r.z = fmaxf(a0.z, 0.f); r.w = fmaxf(a0.w, 0.f);
        *(f32x4*)&h[wave * 4 + 0][lane * 4] = r;
        r.x = fmaxf(a1.x, 0.f); r.y = fmaxf(a1.y, 0.f); r.z = fmaxf(a1.z, 0.f); r.w = fmaxf(a1.w, 0.f);
        *(f32x4*)&h[wave * 4 + 1][lane * 4] = r;
        r.x = fmaxf(a2.x, 0.f); r.y = fmaxf(a2.y, 0.f); r.z = fmaxf(a2.z, 0.f); r.w = fmaxf(a2.w, 0.f);
        *(f32x4*)&h[wave * 4 + 2][lane * 4] = r;
        r.x = fmaxf(a3.x, 0.f); r.y = fmaxf(a3.y, 0.f); r.z = fmaxf(a3.z, 0.f); r.w = fmaxf(a3.w, 0.f);
        *(f32x4*)&h[wave * 4 + 3][lane * 4] = r;
    }
    __syncthreads();

    // ---- phase 2: S2[rt*16 + 0..15][ct*16 + 0..15] = h @ W2
    const int rt = wave >> 2;        // 0..1 row-tile
    const int ct = wave & 3;         // 0..3 col-tile
    f32x4 acc2 = {0.f, 0.f, 0.f, 0.f};
    const ushort_t* bh = BtHi + (size_t)(ct * 16 + l15) * HIDD;
    const ushort_t* bl = BtLo + (size_t)(ct * 16 + l15) * HIDD;
    #pragma unroll
    for (int ks = 0; ks < 8; ++ks) {
        const int ko = ks * 32 + quad * 8;
        const float* ap = &h[rt * 16 + l15][ko];
        float4 v0 = *(const float4*)ap;
        float4 v1 = *(const float4*)(ap + 4);
        bf16x8 aH, aL;
        split8(v0, v1, aH, aL);
        bf16x8 bH = *(const bf16x8*)(bh + ko);
        bf16x8 bL = *(const bf16x8*)(bl + ko);
        acc2 = __builtin_amdgcn_mfma_f32_16x16x32_bf16(aH, bH, acc2, 0, 0, 0);
        acc2 = __builtin_amdgcn_mfma_f32_16x16x32_bf16(aL, bH, acc2, 0, 0, 0);
        acc2 = __builtin_amdgcn_mfma_f32_16x16x32_bf16(aH, bL, acc2, 0, 0, 0);
    }
    // C layout: col = l15 (within tile), row = quad*4 + r (within tile)
    #pragma unroll
    for (int r = 0; r < 4; ++r) {
        const int node = nbase + rt * 16 + quad * 4 + r;
        S2[(size_t)node * OUTD + ct * 16 + l15] = (_Float16)acc2[r];
    }
}

// ---------------------------------------------------------------- SpMM layer 2 + softmax
// wave handles 4 nodes INTERLEAVED (4 load streams); lane = feature (64).
__global__ __launch_bounds__(256) void spmm_softmax_k(
    const int* __restrict__ rowptr, const int2* __restrict__ esw,
    const _Float16* __restrict__ X, float* __restrict__ out)
{
    const int wave = threadIdx.x >> 6;
    const int lane = threadIdx.x & 63;
    const int nw   = blockIdx.x * 16 + wave * 4;

    int beg0 = rowptr[nw],     end0 = rowptr[nw + 1];
    int beg1 = rowptr[nw + 1], end1 = rowptr[nw + 2];
    int beg2 = rowptr[nw + 2], end2 = rowptr[nw + 3];
    int beg3 = rowptr[nw + 3], end3 = rowptr[nw + 4];
    int maxd = max(max(end0 - beg0, end1 - beg1), max(end2 - beg2, end3 - beg3));

    float acc[4] = {0.f, 0.f, 0.f, 0.f};
    #pragma unroll 2
    for (int j = 0; j < maxd; ++j) {
        if (beg0 + j < end0) {
            int2 sw = esw[beg0 + j];
            acc[0] += __int_as_float(sw.y) * (float)X[(size_t)sw.x * OUTD + lane];
        }
        if (beg1 + j < end1) {
            int2 sw = esw[beg1 + j];
            acc[1] += __int_as_float(sw.y) * (float)X[(size_t)sw.x * OUTD + lane];
        }
        if (beg2 + j < end2) {
            int2 sw = esw[beg2 + j];
            acc[2] += __int_as_float(sw.y) * (float)X[(size_t)sw.x * OUTD + lane];
        }
        if (beg3 + j < end3) {
            int2 sw = esw[beg3 + j];
            acc[3] += __int_as_float(sw.y) * (float)X[(size_t)sw.x * OUTD + lane];
        }
    }
    #pragma unroll
    for (int i = 0; i < 4; ++i) {
        float a = acc[i];
        float mx = a;
        #pragma unroll
        for (int off = 32; off > 0; off >>= 1) mx = fmaxf(mx, __shfl_xor(mx, off));
        float ex = __expf(a - mx);
        float sm = ex;
        #pragma unroll
        for (int off = 32; off > 0; off >>= 1) sm += __shfl_xor(sm, off);
        out[(size_t)(nw + i) * OUTD + lane] = ex / sm;
    }
}

// ---------------------------------------------------------------- launch
extern "C" void kernel_launch(void* const* d_in, const int* in_sizes, int n_in,
                              void* d_out, int out_size, void* d_ws, size_t ws_size,
                              hipStream_t stream) {
    const float* x  = (const float*)d_in[0];
    const int*   ei = (const int*)d_in[1];
    const float* ew = (const float*)d_in[2];
    const float* W1 = (const float*)d_in[3];
    const float* W2 = (const float*)d_in[4];
    float* out = (float*)d_out;
    const int* src = ei;        // edge_index row 0
    const int* dst = ei + NE;   // edge_index row 1

    char* ws = (char*)d_ws;
    size_t o = 0;
    auto take = [&](size_t bytes) -> void* {
        void* p = (void*)(ws + o);
        o += (bytes + 255) & ~(size_t)255;
        return p;
    };
    _Float16* S1      = (_Float16*)take((size_t)NN * HIDD * 2);   // 51.2 MB fp16 gather table
    _Float16* S2      = (_Float16*)take((size_t)NN * OUTD * 2);   // 12.8 MB
    int2*     binned  = (int2*    )take((size_t)NE * 8);          // 25.6 MB (CSR scratch)
    ushort_t* W1tHi   = (ushort_t*)take((size_t)IND * HIDD * 2);
    ushort_t* W1tLo   = (ushort_t*)take((size_t)IND * HIDD * 2);
    ushort_t* W2tHi   = (ushort_t*)take((size_t)HIDD * OUTD * 2);
    ushort_t* W2tLo   = (ushort_t*)take((size_t)HIDD * OUTD * 2);
    int*      rowptr  = (int*     )take((size_t)(NN + 1) * 4);
    int*      bHist   = (int*     )take(NBKT * 4);
    int*      bStart  = (int*     )take((NBKT + 1) * 4);
    int*      bCursor = (int*     )take(NBKT * 4);
    int2*     esw     = (int2*    )take((size_t)NE * 8);          // 25.6 MB
    (void)in_sizes; (void)n_in; (void)out_size; (void)ws_size;

    const int MB = (NN + 127) / 128;          // 782

    hipMemsetAsync(bHist, 0, NBKT * 4, stream);
    splitw_k<<<(IND * HIDD + 255) / 256, 256, 0, stream>>>(W1, W1tHi, W1tLo, IND, HIDD);
    splitw_k<<<(HIDD * OUTD + 255) / 256, 256, 0, stream>>>(W2, W2tHi, W2tLo, HIDD, OUTD);

    // CSR build: bucket hist -> scan -> bin -> per-bucket node sort
    bhist_k<<<(NE + 1023) / 1024, 256, 0, stream>>>(dst, bHist);
    bscan_k<<<1, 128, 0, stream>>>(bHist, bStart, bCursor);
    phase1_k<<<(NE + P1E - 1) / P1E, 256, 0, stream>>>(src, dst, ew, bCursor, binned);
    phase2_k<<<NBKT, 256, 0, stream>>>(bStart, binned, rowptr, esw);

    // layer 1: S1 = x @ W1 (split-bf16 3-MFMA, global_load_lds staging, fp16 out)
    gemm1_k<<<dim3(2, MB), 256, 0, stream>>>(x, W1tHi, W1tLo, S1);
    // fused: S2 = relu(A_sp @ S1) @ W2  (32 nodes/block, interleaved gather, MFMA tail)
    spmm_relu_gemm2_k<<<NN / 32, 512, 0, stream>>>(rowptr, esw, S1, W2tHi, W2tLo, S2);
    // out = softmax(A_sp @ S2), interleaved gather
    spmm_softmax_k<<<NN / 16, 256, 0, stream>>>(rowptr, esw, S2, out);
}

// Round 6
// 889.012 us; speedup vs baseline: 1.4305x; 1.4305x over previous
//
#include <hip/hip_runtime.h>
#include <hip/hip_bf16.h>

typedef __attribute__((ext_vector_type(8))) short bf16x8;   // 8 bf16 = 4 VGPRs (MFMA A/B frag)
typedef __attribute__((ext_vector_type(4))) float f32x4;    // MFMA C/D frag
typedef __attribute__((ext_vector_type(4))) _Float16 f16x4; // 8 B gather unit
typedef unsigned short ushort_t;

#define NN   100000
#define NE   3200000
#define IND  512
#define HIDD 256
#define OUTD 64

#define NBKT 98            // buckets of 1024 nodes: ceil(100000/1024)=98
#define P1E  2048          // edges per phase-1 block
#define MPAN 782           // m-panels in gemm1: ceil(100000/128)

// bf16 helpers (RTNE, manual bit math — no NaN inputs in this problem)
__device__ __forceinline__ ushort_t f2bf(float a) {
    unsigned u = __float_as_uint(a);
    unsigned r = (u + 0x7FFFu + ((u >> 16) & 1u)) >> 16;
    return (ushort_t)r;
}
__device__ __forceinline__ float bf2f(ushort_t b) {
    return __uint_as_float(((unsigned)b) << 16);
}

union U8 { ushort_t us[8]; unsigned u32[4]; uint4 v; };

// async global->LDS, 16 B per lane (linear LDS dest = base + lane*16)
#define GLOAD_LDS16(gp, lp) \
    __builtin_amdgcn_global_load_lds( \
        (const __attribute__((address_space(1))) void*)(const void*)(gp), \
        (__attribute__((address_space(3))) void*)(void*)(lp), 16, 0, 0)

// register hi/lo split of 8 f32 -> two bf16x8 (hi = truncate, lo = truncate of
// the exact residual; dropped lo*lo term <= 2^-17 rel — invisible vs fp16 out)
__device__ __forceinline__ void split8(float4 v0, float4 v1, bf16x8& aH, bf16x8& aL) {
    float vv[8] = {v0.x, v0.y, v0.z, v0.w, v1.x, v1.y, v1.z, v1.w};
    U8 H, L;
    #pragma unroll
    for (int j = 0; j < 4; ++j) {
        unsigned u0 = __float_as_uint(vv[2 * j]);
        unsigned u1 = __float_as_uint(vv[2 * j + 1]);
        H.u32[j] = __builtin_amdgcn_perm(u1, u0, 0x07060302u);
        float r0 = vv[2 * j]     - __uint_as_float(u0 & 0xFFFF0000u);
        float r1 = vv[2 * j + 1] - __uint_as_float(u1 & 0xFFFF0000u);
        L.u32[j] = __builtin_amdgcn_perm(__float_as_uint(r1),
                                         __float_as_uint(r0), 0x07060302u);
    }
    aH = *(const bf16x8*)&H.v;
    aL = *(const bf16x8*)&L.v;
}

// ------------------------------------------------- weight transpose + hi/lo split
__global__ void splitw_k(const float* __restrict__ in, ushort_t* __restrict__ thi,
                         ushort_t* __restrict__ tlo, int R, int C) {
    int i = blockIdx.x * 256 + threadIdx.x;
    if (i < R * C) {
        int r = i / C, c = i % C;
        float a = in[i];
        ushort_t h = f2bf(a);
        thi[(size_t)c * R + r] = h;
        tlo[(size_t)c * R + r] = f2bf(a - bf2f(h));
    }
}

// ------------------------------------------------- layer-1 GEMM: S1 = x @ W1 (fp16 out)
// m97-style: global_load_lds staging (no ds_writes), single LDS buffer, 2 barriers/k-step.
// A stays f32 in LDS; hi/lo split happens in registers after ds_read.
// Both LDS tiles XOR-swizzled on source AND read (rule 21) -> 2-way (free) bank pattern.
// 128x128 tile, wave=64x64 (acc[4][4]), 3 blocks/CU.
// Grid is 1D + XCD-PAIRED: panel p's two n-blocks sit at dispatch slots d and
// d+8 (same XCD under round-robin) so the second n-block's x-panel reads are
// L2 hits instead of a second fabric fetch.
__global__ __launch_bounds__(256, 3) void gemm1_k(
    const float* __restrict__ A, const ushort_t* __restrict__ BtHi,
    const ushort_t* __restrict__ BtLo, _Float16* __restrict__ C)
{
    const int M = NN, N = HIDD, K = IND;
    __shared__ __align__(16) float    sA [128 * 32];   // 16 KiB, swizzled
    __shared__ __align__(16) ushort_t sBh[128 * 32];   // 8 KiB, swizzled
    __shared__ __align__(16) ushort_t sBl[128 * 32];   // 8 KiB

    const int bid   = blockIdx.x;
    const int grp   = bid >> 4;          // group of 16 dispatches = 8 panels x 2 n-blocks
    const int rr_   = bid & 15;
    const int panel = grp * 8 + (rr_ & 7);
    if (panel >= MPAN) return;           // pad blocks (grid rounded to 16)
    const int m0 = panel * 128;
    const int n0 = (rr_ >> 3) * 128;

    const int tid  = threadIdx.x;
    const int wave = tid >> 6;
    const int lane = tid & 63;
    const int quad = lane >> 4;
    const int l15  = lane & 15;
    const int wr   = wave >> 1;          // 0..1 (row half)
    const int wc   = wave & 1;           // 0..1 (col half)

    // ---- staging descriptors (k0-invariant). A: 128 rows x 32 f32, 16B-block
    // swizzle blk' = blk ^ ((r&3)<<1) ^ ((r>>2)&1) applied to the GLOBAL source.
    const float* aSrc[4];
    float*       aDst[4];
    #pragma unroll
    for (int it = 0; it < 4; ++it) {
        int f = it * 256 + tid;          // 16B block 0..1023
        int r = f >> 3;                  // 8 blocks per row
        int bp = (f & 7) ^ ((r & 3) << 1) ^ ((r >> 2) & 1);
        int gr = m0 + r; if (gr >= M) gr = M - 1;   // clamp; results row-guarded on store
        aSrc[it] = A + (size_t)gr * K + bp * 4;
        aDst[it] = &sA[f * 4];
    }
    // B: 128 rows (cols of C) x 32 bf16, block swizzle q' = q ^ ((r>>1)&3)
    const ushort_t* bhSrc[2]; const ushort_t* blSrc[2];
    ushort_t* bhDst[2]; ushort_t* blDst[2];
    #pragma unroll
    for (int it = 0; it < 2; ++it) {
        int f = it * 256 + tid;          // block 0..511
        int r = f >> 2;                  // 4 blocks per row
        int qp = (f & 3) ^ ((r >> 1) & 3);
        bhSrc[it] = BtHi + (size_t)(n0 + r) * K + qp * 8;
        blSrc[it] = BtLo + (size_t)(n0 + r) * K + qp * 8;
        bhDst[it] = &sBh[f * 8];
        blDst[it] = &sBl[f * 8];
    }

    // ---- fragment read offsets with the matching read-side swizzle
    int aOff[4][2];
    #pragma unroll
    for (int ms = 0; ms < 4; ++ms) {
        int rA = wr * 64 + ms * 16 + l15;
        int sw = ((rA & 3) << 1) ^ ((rA >> 2) & 1);
        int cb = quad << 1;
        aOff[ms][0] = rA * 32 + (((cb    ) ^ sw) << 2);
        aOff[ms][1] = rA * 32 + (((cb | 1) ^ sw) << 2);
    }
    int bOff[4];
    #pragma unroll
    for (int ns = 0; ns < 4; ++ns) {
        int rB = wc * 64 + ns * 16 + l15;
        bOff[ns] = rB * 32 + (quad ^ ((rB >> 1) & 3)) * 8;
    }

    f32x4 acc[4][4] = {};

    for (int k0 = 0; k0 < K; k0 += 32) {
        #pragma unroll
        for (int it = 0; it < 4; ++it) GLOAD_LDS16(aSrc[it] + k0, aDst[it]);
        #pragma unroll
        for (int it = 0; it < 2; ++it) {
            GLOAD_LDS16(bhSrc[it] + k0, bhDst[it]);
            GLOAD_LDS16(blSrc[it] + k0, blDst[it]);
        }
        __syncthreads();

        bf16x8 aH[4], aL[4];
        #pragma unroll
        for (int ms = 0; ms < 4; ++ms) {
            float4 v0 = *(const float4*)&sA[aOff[ms][0]];
            float4 v1 = *(const float4*)&sA[aOff[ms][1]];
            split8(v0, v1, aH[ms], aL[ms]);
        }

        #pragma unroll
        for (int ns = 0; ns < 4; ++ns) {
            bf16x8 bH = *(const bf16x8*)&sBh[bOff[ns]];
            bf16x8 bL = *(const bf16x8*)&sBl[bOff[ns]];
            #pragma unroll
            for (int ms = 0; ms < 4; ++ms) {
                acc[ms][ns] = __builtin_amdgcn_mfma_f32_16x16x32_bf16(aH[ms], bH, acc[ms][ns], 0, 0, 0);
                acc[ms][ns] = __builtin_amdgcn_mfma_f32_16x16x32_bf16(aL[ms], bH, acc[ms][ns], 0, 0, 0);
                acc[ms][ns] = __builtin_amdgcn_mfma_f32_16x16x32_bf16(aH[ms], bL, acc[ms][ns], 0, 0, 0);
            }
        }
        __syncthreads();
    }

    #pragma unroll
    for (int ms = 0; ms < 4; ++ms) {
        int row = m0 + wr * 64 + ms * 16 + quad * 4;
        #pragma unroll
        for (int ns = 0; ns < 4; ++ns) {
            int col = n0 + wc * 64 + ns * 16 + l15;
            #pragma unroll
            for (int r = 0; r < 4; ++r)
                if (row + r < M) C[(size_t)(row + r) * N + col] = (_Float16)acc[ms][ns][r];
        }
    }
}

// ---------------------------------------------------------------- CSR build (binned)
__global__ __launch_bounds__(256) void bhist_k(const int* __restrict__ dst,
                                               int* __restrict__ bucketHist) {
    __shared__ int h[NBKT];
    int t = threadIdx.x;
    if (t < NBKT) h[t] = 0;
    __syncthreads();
    #pragma unroll
    for (int j = 0; j < 4; ++j) {
        int e = blockIdx.x * 1024 + t + j * 256;
        if (e < NE) atomicAdd(&h[dst[e] >> 10], 1);
    }
    __syncthreads();
    if (t < NBKT && h[t]) atomicAdd(&bucketHist[t], h[t]);
}

__global__ __launch_bounds__(128) void bscan_k(const int* __restrict__ bucketHist,
                                               int* __restrict__ bucketStart,
                                               int* __restrict__ bucketCursor) {
    __shared__ int s[128];
    int t = threadIdx.x;
    int v = (t < NBKT) ? bucketHist[t] : 0;
    s[t] = v;
    for (int off = 1; off < 128; off <<= 1) {
        __syncthreads();
        int a = (t >= off) ? s[t - off] : 0;
        __syncthreads();
        s[t] += a;
    }
    __syncthreads();
    if (t < NBKT) { bucketStart[t] = s[t] - v; bucketCursor[t] = s[t] - v; }
    if (t == NBKT - 1) bucketStart[NBKT] = s[t];
}

__global__ __launch_bounds__(256) void phase1_k(
    const int* __restrict__ src, const int* __restrict__ dst,
    const float* __restrict__ w, int* __restrict__ bucketCursor,
    int2* __restrict__ binned)
{
    __shared__ int2 raw[P1E];
    __shared__ int2 ord[P1E];
    __shared__ ushort_t rbkt[P1E], obkt[P1E];
    __shared__ int hist[128], excl[128], cursor[128], gbase[128], stmp[128];

    int t = threadIdx.x;
    if (t < 128) hist[t] = 0;
    __syncthreads();

    int e0 = blockIdx.x * P1E;
    #pragma unroll
    for (int j = 0; j < P1E / 256; ++j) {
        int li = t + j * 256;
        int e = e0 + li;
        if (e < NE) {
            int d = dst[e];
            int b = d >> 10;
            raw[li] = make_int2(src[e] | ((d & 1023) << 17), __float_as_int(w[e]));
            rbkt[li] = (ushort_t)b;
            atomicAdd(&hist[b], 1);
        } else rbkt[li] = 0xFFFFu;
    }
    __syncthreads();
    int v = (t < 128) ? hist[t] : 0;
    if (t < 128) stmp[t] = v;
    for (int off = 1; off < 128; off <<= 1) {
        __syncthreads();
        int a = (t < 128 && t >= off) ? stmp[t - off] : 0;
        __syncthreads();
        if (t < 128) stmp[t] += a;
    }
    __syncthreads();
    if (t < 128) { excl[t] = stmp[t] - v; cursor[t] = stmp[t] - v; }
    if (t < NBKT) gbase[t] = atomicAdd(&bucketCursor[t], hist[t]);
    __syncthreads();
    #pragma unroll
    for (int j = 0; j < P1E / 256; ++j) {
        int li = t + j * 256;
        ushort_t b = rbkt[li];
        if (b != 0xFFFFu) {
            int p = atomicAdd(&cursor[b], 1);
            ord[p] = raw[li];
            obkt[p] = b;
        }
    }
    __syncthreads();
    int tot = excl[NBKT - 1] + hist[NBKT - 1];
    #pragma unroll
    for (int j = 0; j < P1E / 256; ++j) {
        int li = t + j * 256;
        if (li < tot) {
            int b = obkt[li];
            binned[(size_t)gbase[b] + (li - excl[b])] = ord[li];
        }
    }
}

__global__ __launch_bounds__(256) void phase2_k(
    const int* __restrict__ bucketStart, const int2* __restrict__ binned,
    int* __restrict__ rowptr, int2* __restrict__ esw)
{
    __shared__ int cnt[1024], ex[1024], cur[1024], wsum[256];
    int t = threadIdx.x, blk = blockIdx.x;
    int gb = bucketStart[blk], ge = bucketStart[blk + 1];
    #pragma unroll
    for (int j = 0; j < 4; ++j) cnt[t + j * 256] = 0;
    __syncthreads();
    for (int e = gb + t; e < ge; e += 256)
        atomicAdd(&cnt[(binned[e].x >> 17) & 1023], 1);
    __syncthreads();
    int b4 = t * 4;
    int l0 = cnt[b4], l1 = cnt[b4 + 1], l2 = cnt[b4 + 2], l3 = cnt[b4 + 3];
    int ls = l0 + l1 + l2 + l3;
    wsum[t] = ls;
    for (int off = 1; off < 256; off <<= 1) {
        __syncthreads();
        int a = (t >= off) ? wsum[t - off] : 0;
        __syncthreads();
        wsum[t] += a;
    }
    __syncthreads();
    int be = wsum[t] - ls;
    ex[b4] = be;            cur[b4] = be;
    ex[b4 + 1] = be + l0;     cur[b4 + 1] = be + l0;
    ex[b4 + 2] = be + l0 + l1;  cur[b4 + 2] = be + l0 + l1;
    ex[b4 + 3] = be + l0 + l1 + l2; cur[b4 + 3] = be + l0 + l1 + l2;
    __syncthreads();
    int n0 = blk << 10;
    #pragma unroll
    for (int j = 0; j < 4; ++j) {
        int i = b4 + j;
        if (n0 + i < NN) rowptr[n0 + i] = gb + ex[i];
    }
    if (blk == NBKT - 1 && t == 0) rowptr[NN] = NE;
    for (int e = gb + t; e < ge; e += 256) {
        int2 en = binned[e];
        int d = (en.x >> 17) & 1023;
        int p = atomicAdd(&cur[d], 1);
        esw[(size_t)gb + p] = make_int2(en.x & 0x1FFFF, en.y);
    }
}

// ---------------------------------------------------------------- fused SpMM1+ReLU+GEMM2
// (R2-measured form, 257 µs.) Block = 16 nodes (4 waves x 4 nodes). Phase 1:
// each wave gathers+ReLUs its 4 h-rows SEQUENTIALLY with unroll 8 (the proven
// high-MLP inner loop: ~8 loads in flight, VGPR ~40 — R3/R5 showed any
// "smarter" schedule serializes). Phase 2: wave w computes S2 cols
// [16w,16w+16) for all 16 nodes via register hi/lo split + 3-MFMA; B-frags
// from the L2-resident 64 KB W2t tables.
__global__ __launch_bounds__(256) void spmm_relu_gemm2_k(
    const int* __restrict__ rowptr, const int2* __restrict__ esw,
    const _Float16* __restrict__ X, const ushort_t* __restrict__ BtHi,
    const ushort_t* __restrict__ BtLo, _Float16* __restrict__ S2)
{
    __shared__ __align__(16) float h[16][260];

    const int wave  = threadIdx.x >> 6;
    const int lane  = threadIdx.x & 63;
    const int quad  = lane >> 4;
    const int l15   = lane & 15;
    const int nbase = blockIdx.x * 16;

    // ---- phase 1: gather 4 nodes per wave
    const _Float16* Xl = X + lane * 4;
    #pragma unroll
    for (int i = 0; i < 4; ++i) {
        const int ln   = wave * 4 + i;
        const int node = nbase + ln;
        const int beg = rowptr[node], end = rowptr[node + 1];
        f32x4 acc = {0.f, 0.f, 0.f, 0.f};
        #pragma unroll 8
        for (int e = beg; e < end; ++e) {
            int2 sw = esw[e];
            float w = __int_as_float(sw.y);
            f16x4 v = *(const f16x4*)(Xl + (size_t)sw.x * HIDD);
            acc.x += (float)v[0] * w;
            acc.y += (float)v[1] * w;
            acc.z += (float)v[2] * w;
            acc.w += (float)v[3] * w;
        }
        f32x4 r;
        r.x = fmaxf(acc.x, 0.f);
        r.y = fmaxf(acc.y, 0.f);
        r.z = fmaxf(acc.z, 0.f);
        r.w = fmaxf(acc.w, 0.f);
        *(f32x4*)&h[ln][lane * 4] = r;
    }
    __syncthreads();

    // ---- phase 2: S2[16 nodes][16 cols of this wave] = h @ W2
    f32x4 acc2 = {0.f, 0.f, 0.f, 0.f};
    const ushort_t* bh = BtHi + (size_t)(wave * 16 + l15) * HIDD;
    const ushort_t* bl = BtLo + (size_t)(wave * 16 + l15) * HIDD;
    #pragma unroll
    for (int ks = 0; ks < 8; ++ks) {
        const int ko = ks * 32 + quad * 8;
        const float* ap = &h[l15][ko];
        float4 v0 = *(const float4*)ap;
        float4 v1 = *(const float4*)(ap + 4);
        bf16x8 aH, aL;
        split8(v0, v1, aH, aL);
        bf16x8 bH = *(const bf16x8*)(bh + ko);
        bf16x8 bL = *(const bf16x8*)(bl + ko);
        acc2 = __builtin_amdgcn_mfma_f32_16x16x32_bf16(aH, bH, acc2, 0, 0, 0);
        acc2 = __builtin_amdgcn_mfma_f32_16x16x32_bf16(aL, bH, acc2, 0, 0, 0);
        acc2 = __builtin_amdgcn_mfma_f32_16x16x32_bf16(aH, bL, acc2, 0, 0, 0);
    }
    // C layout: col = l15, row = quad*4 + r (local node index)
    #pragma unroll
    for (int r = 0; r < 4; ++r) {
        const int node = nbase + quad * 4 + r;
        S2[(size_t)node * OUTD + wave * 16 + l15] = (_Float16)acc2[r];
    }
}

// ---------------------------------------------------------------- SpMM layer 2 + softmax
// (R2-measured form.) one wave per node; lane = feature (64). fp16 gather table.
__global__ __launch_bounds__(256) void spmm_softmax_k(
    const int* __restrict__ rowptr, const int2* __restrict__ esw,
    const _Float16* __restrict__ X, float* __restrict__ out)
{
    int node = blockIdx.x * 4 + (threadIdx.x >> 6);
    int lane = threadIdx.x & 63;
    int beg = rowptr[node], end = rowptr[node + 1];
    float acc = 0.f;
    #pragma unroll 4
    for (int e = beg; e < end; ++e) {
        int2 sw = esw[e];
        acc += __int_as_float(sw.y) * (float)X[(size_t)sw.x * OUTD + lane];
    }
    float mx = acc;
    #pragma unroll
    for (int off = 32; off > 0; off >>= 1) mx = fmaxf(mx, __shfl_xor(mx, off));
    float ex = __expf(acc - mx);
    float sm = ex;
    #pragma unroll
    for (int off = 32; off > 0; off >>= 1) sm += __shfl_xor(sm, off);
    out[(size_t)node * OUTD + lane] = ex / sm;
}

// ---------------------------------------------------------------- launch
extern "C" void kernel_launch(void* const* d_in, const int* in_sizes, int n_in,
                              void* d_out, int out_size, void* d_ws, size_t ws_size,
                              hipStream_t stream) {
    const float* x  = (const float*)d_in[0];
    const int*   ei = (const int*)d_in[1];
    const float* ew = (const float*)d_in[2];
    const float* W1 = (const float*)d_in[3];
    const float* W2 = (const float*)d_in[4];
    float* out = (float*)d_out;
    const int* src = ei;        // edge_index row 0
    const int* dst = ei + NE;   // edge_index row 1

    char* ws = (char*)d_ws;
    size_t o = 0;
    auto take = [&](size_t bytes) -> void* {
        void* p = (void*)(ws + o);
        o += (bytes + 255) & ~(size_t)255;
        return p;
    };
    _Float16* S1      = (_Float16*)take((size_t)NN * HIDD * 2);   // 51.2 MB fp16 gather table
    _Float16* S2      = (_Float16*)take((size_t)NN * OUTD * 2);   // 12.8 MB
    int2*     binned  = (int2*    )take((size_t)NE * 8);          // 25.6 MB (CSR scratch)
    ushort_t* W1tHi   = (ushort_t*)take((size_t)IND * HIDD * 2);
    ushort_t* W1tLo   = (ushort_t*)take((size_t)IND * HIDD * 2);
    ushort_t* W2tHi   = (ushort_t*)take((size_t)HIDD * OUTD * 2);
    ushort_t* W2tLo   = (ushort_t*)take((size_t)HIDD * OUTD * 2);
    int*      rowptr  = (int*     )take((size_t)(NN + 1) * 4);
    int*      bHist   = (int*     )take(NBKT * 4);
    int*      bStart  = (int*     )take((NBKT + 1) * 4);
    int*      bCursor = (int*     )take(NBKT * 4);
    int2*     esw     = (int2*    )take((size_t)NE * 8);          // 25.6 MB
    (void)in_sizes; (void)n_in; (void)out_size; (void)ws_size;

    hipMemsetAsync(bHist, 0, NBKT * 4, stream);
    splitw_k<<<(IND * HIDD + 255) / 256, 256, 0, stream>>>(W1, W1tHi, W1tLo, IND, HIDD);
    splitw_k<<<(HIDD * OUTD + 255) / 256, 256, 0, stream>>>(W2, W2tHi, W2tLo, HIDD, OUTD);

    // CSR build: bucket hist -> scan -> bin -> per-bucket node sort
    bhist_k<<<(NE + 1023) / 1024, 256, 0, stream>>>(dst, bHist);
    bscan_k<<<1, 128, 0, stream>>>(bHist, bStart, bCursor);
    phase1_k<<<(NE + P1E - 1) / P1E, 256, 0, stream>>>(src, dst, ew, bCursor, binned);
    phase2_k<<<NBKT, 256, 0, stream>>>(bStart, binned, rowptr, esw);

    // layer 1: S1 = x @ W1 (split-bf16 3-MFMA, gload_lds staging, XCD-paired grid)
    const int G1 = ((MPAN + 7) / 8) * 16;   // 98 groups x 16 = 1568 (4 pad blocks)
    gemm1_k<<<G1, 256, 0, stream>>>(x, W1tHi, W1tLo, S1);
    // fused: S2 = relu(A_sp @ S1) @ W2  (16 nodes/block, sequential gather, MFMA tail)
    spmm_relu_gemm2_k<<<NN / 16, 256, 0, stream>>>(rowptr, esw, S1, W2tHi, W2tLo, S2);
    // out = softmax(A_sp @ S2)
    spmm_softmax_k<<<NN / 4, 256, 0, stream>>>(rowptr, esw, S2, out);
}

// Round 7
// 828.049 us; speedup vs baseline: 1.5358x; 1.0736x over previous
//
#include <hip/hip_runtime.h>
#include <hip/hip_bf16.h>

typedef __attribute__((ext_vector_type(8))) short bf16x8;      // 8 bf16 = 4 VGPRs (MFMA A/B frag)
typedef __attribute__((ext_vector_type(4))) float f32x4;       // MFMA C/D frag
typedef __attribute__((ext_vector_type(8))) float f32x8;       // wide gather accumulator
typedef __attribute__((ext_vector_type(4))) _Float16 f16x4;    // 8 B gather unit
typedef __attribute__((ext_vector_type(8))) _Float16 f16x8;    // 16 B gather unit
typedef unsigned short ushort_t;

#define NN   100000
#define NE   3200000
#define IND  512
#define HIDD 256
#define OUTD 64

#define NBKT 98            // buckets of 1024 nodes: ceil(100000/1024)=98
#define P1E  2048          // edges per phase-1 block
#define MPAN 782           // m-panels in gemm1: ceil(100000/128)

// bf16 helpers (RTNE, manual bit math — no NaN inputs in this problem)
__device__ __forceinline__ ushort_t f2bf(float a) {
    unsigned u = __float_as_uint(a);
    unsigned r = (u + 0x7FFFu + ((u >> 16) & 1u)) >> 16;
    return (ushort_t)r;
}
__device__ __forceinline__ float bf2f(ushort_t b) {
    return __uint_as_float(((unsigned)b) << 16);
}

union U8 { ushort_t us[8]; unsigned u32[4]; uint4 v; };

// async global->LDS, 16 B per lane (linear LDS dest = base + lane*16)
#define GLOAD_LDS16(gp, lp) \
    __builtin_amdgcn_global_load_lds( \
        (const __attribute__((address_space(1))) void*)(const void*)(gp), \
        (__attribute__((address_space(3))) void*)(void*)(lp), 16, 0, 0)

// register hi/lo split of 8 f32 -> two bf16x8 (hi = truncate, lo = truncate of
// the exact residual; dropped lo*lo term <= 2^-17 rel — invisible vs fp16 out)
__device__ __forceinline__ void split8(float4 v0, float4 v1, bf16x8& aH, bf16x8& aL) {
    float vv[8] = {v0.x, v0.y, v0.z, v0.w, v1.x, v1.y, v1.z, v1.w};
    U8 H, L;
    #pragma unroll
    for (int j = 0; j < 4; ++j) {
        unsigned u0 = __float_as_uint(vv[2 * j]);
        unsigned u1 = __float_as_uint(vv[2 * j + 1]);
        H.u32[j] = __builtin_amdgcn_perm(u1, u0, 0x07060302u);
        float r0 = vv[2 * j]     - __uint_as_float(u0 & 0xFFFF0000u);
        float r1 = vv[2 * j + 1] - __uint_as_float(u1 & 0xFFFF0000u);
        L.u32[j] = __builtin_amdgcn_perm(__float_as_uint(r1),
                                         __float_as_uint(r0), 0x07060302u);
    }
    aH = *(const bf16x8*)&H.v;
    aL = *(const bf16x8*)&L.v;
}

// ------------------------------------------------- weight transpose + hi/lo split
__global__ void splitw_k(const float* __restrict__ in, ushort_t* __restrict__ thi,
                         ushort_t* __restrict__ tlo, int R, int C) {
    int i = blockIdx.x * 256 + threadIdx.x;
    if (i < R * C) {
        int r = i / C, c = i % C;
        float a = in[i];
        ushort_t h = f2bf(a);
        thi[(size_t)c * R + r] = h;
        tlo[(size_t)c * R + r] = f2bf(a - bf2f(h));
    }
}

// ------------------------------------------------- layer-1 GEMM: S1 = x @ W1 (fp16 out)
// m97-style: global_load_lds staging (no ds_writes), single LDS buffer, 2 barriers/k-step.
// A stays f32 in LDS; hi/lo split happens in registers after ds_read.
// Both LDS tiles XOR-swizzled on source AND read (rule 21) -> 2-way (free) bank pattern.
// 128x128 tile, wave=64x64 (acc[4][4]), 3 blocks/CU. Grid 1D + XCD-PAIRED:
// panel p's two n-blocks at slots d and d+8 (same XCD) -> x-panel L2 reuse.
__global__ __launch_bounds__(256, 3) void gemm1_k(
    const float* __restrict__ A, const ushort_t* __restrict__ BtHi,
    const ushort_t* __restrict__ BtLo, _Float16* __restrict__ C)
{
    const int M = NN, N = HIDD, K = IND;
    __shared__ __align__(16) float    sA [128 * 32];   // 16 KiB, swizzled
    __shared__ __align__(16) ushort_t sBh[128 * 32];   // 8 KiB, swizzled
    __shared__ __align__(16) ushort_t sBl[128 * 32];   // 8 KiB

    const int bid   = blockIdx.x;
    const int grp   = bid >> 4;          // group of 16 dispatches = 8 panels x 2 n-blocks
    const int rr_   = bid & 15;
    const int panel = grp * 8 + (rr_ & 7);
    if (panel >= MPAN) return;           // pad blocks (grid rounded to 16)
    const int m0 = panel * 128;
    const int n0 = (rr_ >> 3) * 128;

    const int tid  = threadIdx.x;
    const int wave = tid >> 6;
    const int lane = tid & 63;
    const int quad = lane >> 4;
    const int l15  = lane & 15;
    const int wr   = wave >> 1;          // 0..1 (row half)
    const int wc   = wave & 1;           // 0..1 (col half)

    // ---- staging descriptors (k0-invariant). A: 128 rows x 32 f32, 16B-block
    // swizzle blk' = blk ^ ((r&3)<<1) ^ ((r>>2)&1) applied to the GLOBAL source.
    const float* aSrc[4];
    float*       aDst[4];
    #pragma unroll
    for (int it = 0; it < 4; ++it) {
        int f = it * 256 + tid;          // 16B block 0..1023
        int r = f >> 3;                  // 8 blocks per row
        int bp = (f & 7) ^ ((r & 3) << 1) ^ ((r >> 2) & 1);
        int gr = m0 + r; if (gr >= M) gr = M - 1;   // clamp; results row-guarded on store
        aSrc[it] = A + (size_t)gr * K + bp * 4;
        aDst[it] = &sA[f * 4];
    }
    // B: 128 rows (cols of C) x 32 bf16, block swizzle q' = q ^ ((r>>1)&3)
    const ushort_t* bhSrc[2]; const ushort_t* blSrc[2];
    ushort_t* bhDst[2]; ushort_t* blDst[2];
    #pragma unroll
    for (int it = 0; it < 2; ++it) {
        int f = it * 256 + tid;          // block 0..511
        int r = f >> 2;                  // 4 blocks per row
        int qp = (f & 3) ^ ((r >> 1) & 3);
        bhSrc[it] = BtHi + (size_t)(n0 + r) * K + qp * 8;
        blSrc[it] = BtLo + (size_t)(n0 + r) * K + qp * 8;
        bhDst[it] = &sBh[f * 8];
        blDst[it] = &sBl[f * 8];
    }

    // ---- fragment read offsets with the matching read-side swizzle
    int aOff[4][2];
    #pragma unroll
    for (int ms = 0; ms < 4; ++ms) {
        int rA = wr * 64 + ms * 16 + l15;
        int sw = ((rA & 3) << 1) ^ ((rA >> 2) & 1);
        int cb = quad << 1;
        aOff[ms][0] = rA * 32 + (((cb    ) ^ sw) << 2);
        aOff[ms][1] = rA * 32 + (((cb | 1) ^ sw) << 2);
    }
    int bOff[4];
    #pragma unroll
    for (int ns = 0; ns < 4; ++ns) {
        int rB = wc * 64 + ns * 16 + l15;
        bOff[ns] = rB * 32 + (quad ^ ((rB >> 1) & 3)) * 8;
    }

    f32x4 acc[4][4] = {};

    for (int k0 = 0; k0 < K; k0 += 32) {
        #pragma unroll
        for (int it = 0; it < 4; ++it) GLOAD_LDS16(aSrc[it] + k0, aDst[it]);
        #pragma unroll
        for (int it = 0; it < 2; ++it) {
            GLOAD_LDS16(bhSrc[it] + k0, bhDst[it]);
            GLOAD_LDS16(blSrc[it] + k0, blDst[it]);
        }
        __syncthreads();

        bf16x8 aH[4], aL[4];
        #pragma unroll
        for (int ms = 0; ms < 4; ++ms) {
            float4 v0 = *(const float4*)&sA[aOff[ms][0]];
            float4 v1 = *(const float4*)&sA[aOff[ms][1]];
            split8(v0, v1, aH[ms], aL[ms]);
        }

        #pragma unroll
        for (int ns = 0; ns < 4; ++ns) {
            bf16x8 bH = *(const bf16x8*)&sBh[bOff[ns]];
            bf16x8 bL = *(const bf16x8*)&sBl[bOff[ns]];
            #pragma unroll
            for (int ms = 0; ms < 4; ++ms) {
                acc[ms][ns] = __builtin_amdgcn_mfma_f32_16x16x32_bf16(aH[ms], bH, acc[ms][ns], 0, 0, 0);
                acc[ms][ns] = __builtin_amdgcn_mfma_f32_16x16x32_bf16(aL[ms], bH, acc[ms][ns], 0, 0, 0);
                acc[ms][ns] = __builtin_amdgcn_mfma_f32_16x16x32_bf16(aH[ms], bL, acc[ms][ns], 0, 0, 0);
            }
        }
        __syncthreads();
    }

    #pragma unroll
    for (int ms = 0; ms < 4; ++ms) {
        int row = m0 + wr * 64 + ms * 16 + quad * 4;
        #pragma unroll
        for (int ns = 0; ns < 4; ++ns) {
            int col = n0 + wc * 64 + ns * 16 + l15;
            #pragma unroll
            for (int r = 0; r < 4; ++r)
                if (row + r < M) C[(size_t)(row + r) * N + col] = (_Float16)acc[ms][ns][r];
        }
    }
}

// ---------------------------------------------------------------- CSR build (binned)
__global__ __launch_bounds__(256) void bhist_k(const int* __restrict__ dst,
                                               int* __restrict__ bucketHist) {
    __shared__ int h[NBKT];
    int t = threadIdx.x;
    if (t < NBKT) h[t] = 0;
    __syncthreads();
    #pragma unroll
    for (int j = 0; j < 4; ++j) {
        int e = blockIdx.x * 1024 + t + j * 256;
        if (e < NE) atomicAdd(&h[dst[e] >> 10], 1);
    }
    __syncthreads();
    if (t < NBKT && h[t]) atomicAdd(&bucketHist[t], h[t]);
}

__global__ __launch_bounds__(128) void bscan_k(const int* __restrict__ bucketHist,
                                               int* __restrict__ bucketStart,
                                               int* __restrict__ bucketCursor) {
    __shared__ int s[128];
    int t = threadIdx.x;
    int v = (t < NBKT) ? bucketHist[t] : 0;
    s[t] = v;
    for (int off = 1; off < 128; off <<= 1) {
        __syncthreads();
        int a = (t >= off) ? s[t - off] : 0;
        __syncthreads();
        s[t] += a;
    }
    __syncthreads();
    if (t < NBKT) { bucketStart[t] = s[t] - v; bucketCursor[t] = s[t] - v; }
    if (t == NBKT - 1) bucketStart[NBKT] = s[t];
}

__global__ __launch_bounds__(256) void phase1_k(
    const int* __restrict__ src, const int* __restrict__ dst,
    const float* __restrict__ w, int* __restrict__ bucketCursor,
    int2* __restrict__ binned)
{
    __shared__ int2 raw[P1E];
    __shared__ int2 ord[P1E];
    __shared__ ushort_t rbkt[P1E], obkt[P1E];
    __shared__ int hist[128], excl[128], cursor[128], gbase[128], stmp[128];

    int t = threadIdx.x;
    if (t < 128) hist[t] = 0;
    __syncthreads();

    int e0 = blockIdx.x * P1E;
    #pragma unroll
    for (int j = 0; j < P1E / 256; ++j) {
        int li = t + j * 256;
        int e = e0 + li;
        if (e < NE) {
            int d = dst[e];
            int b = d >> 10;
            raw[li] = make_int2(src[e] | ((d & 1023) << 17), __float_as_int(w[e]));
            rbkt[li] = (ushort_t)b;
            atomicAdd(&hist[b], 1);
        } else rbkt[li] = 0xFFFFu;
    }
    __syncthreads();
    int v = (t < 128) ? hist[t] : 0;
    if (t < 128) stmp[t] = v;
    for (int off = 1; off < 128; off <<= 1) {
        __syncthreads();
        int a = (t < 128 && t >= off) ? stmp[t - off] : 0;
        __syncthreads();
        if (t < 128) stmp[t] += a;
    }
    __syncthreads();
    if (t < 128) { excl[t] = stmp[t] - v; cursor[t] = stmp[t] - v; }
    if (t < NBKT) gbase[t] = atomicAdd(&bucketCursor[t], hist[t]);
    __syncthreads();
    #pragma unroll
    for (int j = 0; j < P1E / 256; ++j) {
        int li = t + j * 256;
        ushort_t b = rbkt[li];
        if (b != 0xFFFFu) {
            int p = atomicAdd(&cursor[b], 1);
            ord[p] = raw[li];
            obkt[p] = b;
        }
    }
    __syncthreads();
    int tot = excl[NBKT - 1] + hist[NBKT - 1];
    #pragma unroll
    for (int j = 0; j < P1E / 256; ++j) {
        int li = t + j * 256;
        if (li < tot) {
            int b = obkt[li];
            binned[(size_t)gbase[b] + (li - excl[b])] = ord[li];
        }
    }
}

__global__ __launch_bounds__(256) void phase2_k(
    const int* __restrict__ bucketStart, const int2* __restrict__ binned,
    int* __restrict__ rowptr, int2* __restrict__ esw)
{
    __shared__ int cnt[1024], ex[1024], cur[1024], wsum[256];
    int t = threadIdx.x, blk = blockIdx.x;
    int gb = bucketStart[blk], ge = bucketStart[blk + 1];
    #pragma unroll
    for (int j = 0; j < 4; ++j) cnt[t + j * 256] = 0;
    __syncthreads();
    for (int e = gb + t; e < ge; e += 256)
        atomicAdd(&cnt[(binned[e].x >> 17) & 1023], 1);
    __syncthreads();
    int b4 = t * 4;
    int l0 = cnt[b4], l1 = cnt[b4 + 1], l2 = cnt[b4 + 2], l3 = cnt[b4 + 3];
    int ls = l0 + l1 + l2 + l3;
    wsum[t] = ls;
    for (int off = 1; off < 256; off <<= 1) {
        __syncthreads();
        int a = (t >= off) ? wsum[t - off] : 0;
        __syncthreads();
        wsum[t] += a;
    }
    __syncthreads();
    int be = wsum[t] - ls;
    ex[b4] = be;            cur[b4] = be;
    ex[b4 + 1] = be + l0;     cur[b4 + 1] = be + l0;
    ex[b4 + 2] = be + l0 + l1;  cur[b4 + 2] = be + l0 + l1;
    ex[b4 + 3] = be + l0 + l1 + l2; cur[b4 + 3] = be + l0 + l1 + l2;
    __syncthreads();
    int n0 = blk << 10;
    #pragma unroll
    for (int j = 0; j < 4; ++j) {
        int i = b4 + j;
        if (n0 + i < NN) rowptr[n0 + i] = gb + ex[i];
    }
    if (blk == NBKT - 1 && t == 0) rowptr[NN] = NE;
    for (int e = gb + t; e < ge; e += 256) {
        int2 en = binned[e];
        int d = (en.x >> 17) & 1023;
        int p = atomicAdd(&cur[d], 1);
        esw[(size_t)gb + p] = make_int2(en.x & 0x1FFFF, en.y);
    }
}

// ---------------------------------------------------------------- fused SpMM1+ReLU+GEMM2
// Block = 16 nodes (4 waves x 4 nodes). Phase 1, WIDE-LOAD form: lane reads
// 16 B (f16x8); 32 lanes cover one 512 B row, so each load instruction fetches
// TWO edges' rows (half-wave per edge) — 1 KB/instr vs 512 B, 2x bytes in
// flight at the same instruction depth (unroll 4 = 8 edges). Sequential
// single-stream loop preserved (R3/R5 lesson). Halves merged with one
// shfl_xor(32) per node. Odd tail: both halves load the SAME row (one fetch),
// upper half weight 0. Phase 2 unchanged: wave w computes S2 cols [16w,16w+16)
// via register hi/lo split + 3-MFMA; B-frags from L2-resident W2t tables.
__global__ __launch_bounds__(256) void spmm_relu_gemm2_k(
    const int* __restrict__ rowptr, const int2* __restrict__ esw,
    const _Float16* __restrict__ X, const ushort_t* __restrict__ BtHi,
    const ushort_t* __restrict__ BtLo, _Float16* __restrict__ S2)
{
    __shared__ __align__(16) float h[16][260];

    const int wave  = threadIdx.x >> 6;
    const int lane  = threadIdx.x & 63;
    const int quad  = lane >> 4;
    const int l15   = lane & 15;
    const int half  = lane >> 5;     // which edge of the pair
    const int l31   = lane & 31;
    const int nbase = blockIdx.x * 16;

    // ---- phase 1: gather 4 nodes per wave, 2 edges per load instruction
    const _Float16* Xl = X + l31 * 8;
    #pragma unroll
    for (int i = 0; i < 4; ++i) {
        const int ln   = wave * 4 + i;
        const int node = nbase + ln;
        const int beg = rowptr[node], end = rowptr[node + 1];
        f32x8 acc = {0.f, 0.f, 0.f, 0.f, 0.f, 0.f, 0.f, 0.f};
        int e = beg;
        #pragma unroll 4
        for (; e + 1 < end; e += 2) {
            int2 sw = esw[e + half];
            float w = __int_as_float(sw.y);
            f16x8 v = *(const f16x8*)(Xl + (size_t)sw.x * HIDD);
            #pragma unroll
            for (int j = 0; j < 8; ++j) acc[j] += (float)v[j] * w;
        }
        if (e < end) {                       // odd tail: shared row, half 1 w=0
            int2 sw = esw[e];
            float w = half ? 0.f : __int_as_float(sw.y);
            f16x8 v = *(const f16x8*)(Xl + (size_t)sw.x * HIDD);
            #pragma unroll
            for (int j = 0; j < 8; ++j) acc[j] += (float)v[j] * w;
        }
        #pragma unroll
        for (int j = 0; j < 8; ++j) acc[j] += __shfl_xor(acc[j], 32);
        if (half == 0) {
            float4 r0, r1;
            r0.x = fmaxf(acc[0], 0.f); r0.y = fmaxf(acc[1], 0.f);
            r0.z = fmaxf(acc[2], 0.f); r0.w = fmaxf(acc[3], 0.f);
            r1.x = fmaxf(acc[4], 0.f); r1.y = fmaxf(acc[5], 0.f);
            r1.z = fmaxf(acc[6], 0.f); r1.w = fmaxf(acc[7], 0.f);
            *(float4*)&h[ln][l31 * 8]     = r0;
            *(float4*)&h[ln][l31 * 8 + 4] = r1;
        }
    }
    __syncthreads();

    // ---- phase 2: S2[16 nodes][16 cols of this wave] = h @ W2
    f32x4 acc2 = {0.f, 0.f, 0.f, 0.f};
    const ushort_t* bh = BtHi + (size_t)(wave * 16 + l15) * HIDD;
    const ushort_t* bl = BtLo + (size_t)(wave * 16 + l15) * HIDD;
    #pragma unroll
    for (int ks = 0; ks < 8; ++ks) {
        const int ko = ks * 32 + quad * 8;
        const float* ap = &h[l15][ko];
        float4 v0 = *(const float4*)ap;
        float4 v1 = *(const float4*)(ap + 4);
        bf16x8 aH, aL;
        split8(v0, v1, aH, aL);
        bf16x8 bH = *(const bf16x8*)(bh + ko);
        bf16x8 bL = *(const bf16x8*)(bl + ko);
        acc2 = __builtin_amdgcn_mfma_f32_16x16x32_bf16(aH, bH, acc2, 0, 0, 0);
        acc2 = __builtin_amdgcn_mfma_f32_16x16x32_bf16(aL, bH, acc2, 0, 0, 0);
        acc2 = __builtin_amdgcn_mfma_f32_16x16x32_bf16(aH, bL, acc2, 0, 0, 0);
    }
    // C layout: col = l15, row = quad*4 + r (local node index)
    #pragma unroll
    for (int r = 0; r < 4; ++r) {
        const int node = nbase + quad * 4 + r;
        S2[(size_t)node * OUTD + wave * 16 + l15] = (_Float16)acc2[r];
    }
}

// ---------------------------------------------------------------- SpMM layer 2 + softmax
// WIDE-LOAD form: one wave per node; 16 lanes x 8 B cover a 128 B S2 row, so
// each load instruction fetches FOUR edges' rows (lane-group g = lane>>4 owns
// edge e+g). 512 B/instr vs the old 128 B. Two shfl_xor (16,32) merge groups;
// softmax reduces within 16-lane groups; lanes g==0 write f32x4.
__global__ __launch_bounds__(256) void spmm_softmax_k(
    const int* __restrict__ rowptr, const int2* __restrict__ esw,
    const _Float16* __restrict__ X, float* __restrict__ out)
{
    const int node = blockIdx.x * 4 + (threadIdx.x >> 6);
    const int lane = threadIdx.x & 63;
    const int g    = lane >> 4;          // edge slot 0..3
    const int l15  = lane & 15;
    const int beg = rowptr[node], end = rowptr[node + 1];

    f32x4 acc = {0.f, 0.f, 0.f, 0.f};
    const _Float16* Xl = X + l15 * 4;
    int e = beg;
    #pragma unroll 4
    for (; e + 3 < end; e += 4) {
        int2 sw = esw[e + g];
        float w = __int_as_float(sw.y);
        f16x4 v = *(const f16x4*)(Xl + (size_t)sw.x * OUTD);
        acc.x += (float)v[0] * w;
        acc.y += (float)v[1] * w;
        acc.z += (float)v[2] * w;
        acc.w += (float)v[3] * w;
    }
    if (e < end) {                       // tail 1..3 edges: clamp row, zero weight
        int idx = e + g;
        int2 sw = esw[min(idx, end - 1)];
        float w = (idx < end) ? __int_as_float(sw.y) : 0.f;
        f16x4 v = *(const f16x4*)(Xl + (size_t)sw.x * OUTD);
        acc.x += (float)v[0] * w;
        acc.y += (float)v[1] * w;
        acc.z += (float)v[2] * w;
        acc.w += (float)v[3] * w;
    }
    // merge the 4 lane-groups: every lane ends with totals for feats l15*4..+4
    acc.x += __shfl_xor(acc.x, 16); acc.x += __shfl_xor(acc.x, 32);
    acc.y += __shfl_xor(acc.y, 16); acc.y += __shfl_xor(acc.y, 32);
    acc.z += __shfl_xor(acc.z, 16); acc.z += __shfl_xor(acc.z, 32);
    acc.w += __shfl_xor(acc.w, 16); acc.w += __shfl_xor(acc.w, 32);

    float mx = fmaxf(fmaxf(acc.x, acc.y), fmaxf(acc.z, acc.w));
    #pragma unroll
    for (int off = 8; off > 0; off >>= 1) mx = fmaxf(mx, __shfl_xor(mx, off));
    float e0 = __expf(acc.x - mx), e1 = __expf(acc.y - mx);
    float e2 = __expf(acc.z - mx), e3 = __expf(acc.w - mx);
    float sm = e0 + e1 + e2 + e3;
    #pragma unroll
    for (int off = 8; off > 0; off >>= 1) sm += __shfl_xor(sm, off);
    if (g == 0) {
        float inv = 1.f / sm;
        f32x4 r = {e0 * inv, e1 * inv, e2 * inv, e3 * inv};
        *(f32x4*)(out + (size_t)node * OUTD + l15 * 4) = r;
    }
}

// ---------------------------------------------------------------- launch
extern "C" void kernel_launch(void* const* d_in, const int* in_sizes, int n_in,
                              void* d_out, int out_size, void* d_ws, size_t ws_size,
                              hipStream_t stream) {
    const float* x  = (const float*)d_in[0];
    const int*   ei = (const int*)d_in[1];
    const float* ew = (const float*)d_in[2];
    const float* W1 = (const float*)d_in[3];
    const float* W2 = (const float*)d_in[4];
    float* out = (float*)d_out;
    const int* src = ei;        // edge_index row 0
    const int* dst = ei + NE;   // edge_index row 1

    char* ws = (char*)d_ws;
    size_t o = 0;
    auto take = [&](size_t bytes) -> void* {
        void* p = (void*)(ws + o);
        o += (bytes + 255) & ~(size_t)255;
        return p;
    };
    _Float16* S1      = (_Float16*)take((size_t)NN * HIDD * 2);   // 51.2 MB fp16 gather table
    _Float16* S2      = (_Float16*)take((size_t)NN * OUTD * 2);   // 12.8 MB
    int2*     binned  = (int2*    )take((size_t)NE * 8);          // 25.6 MB (CSR scratch)
    ushort_t* W1tHi   = (ushort_t*)take((size_t)IND * HIDD * 2);
    ushort_t* W1tLo   = (ushort_t*)take((size_t)IND * HIDD * 2);
    ushort_t* W2tHi   = (ushort_t*)take((size_t)HIDD * OUTD * 2);
    ushort_t* W2tLo   = (ushort_t*)take((size_t)HIDD * OUTD * 2);
    int*      rowptr  = (int*     )take((size_t)(NN + 1) * 4);
    int*      bHist   = (int*     )take(NBKT * 4);
    int*      bStart  = (int*     )take((NBKT + 1) * 4);
    int*      bCursor = (int*     )take(NBKT * 4);
    int2*     esw     = (int2*    )take((size_t)NE * 8);          // 25.6 MB
    (void)in_sizes; (void)n_in; (void)out_size; (void)ws_size;

    hipMemsetAsync(bHist, 0, NBKT * 4, stream);
    splitw_k<<<(IND * HIDD + 255) / 256, 256, 0, stream>>>(W1, W1tHi, W1tLo, IND, HIDD);
    splitw_k<<<(HIDD * OUTD + 255) / 256, 256, 0, stream>>>(W2, W2tHi, W2tLo, HIDD, OUTD);

    // CSR build: bucket hist -> scan -> bin -> per-bucket node sort
    bhist_k<<<(NE + 1023) / 1024, 256, 0, stream>>>(dst, bHist);
    bscan_k<<<1, 128, 0, stream>>>(bHist, bStart, bCursor);
    phase1_k<<<(NE + P1E - 1) / P1E, 256, 0, stream>>>(src, dst, ew, bCursor, binned);
    phase2_k<<<NBKT, 256, 0, stream>>>(bStart, binned, rowptr, esw);

    // layer 1: S1 = x @ W1 (split-bf16 3-MFMA, gload_lds staging, XCD-paired grid)
    const int G1 = ((MPAN + 7) / 8) * 16;   // 98 groups x 16 = 1568 (4 pad blocks)
    gemm1_k<<<G1, 256, 0, stream>>>(x, W1tHi, W1tLo, S1);
    // fused: S2 = relu(A_sp @ S1) @ W2  (16 nodes/block, 2-edge wide gather, MFMA tail)
    spmm_relu_gemm2_k<<<NN / 16, 256, 0, stream>>>(rowptr, esw, S1, W2tHi, W2tLo, S2);
    // out = softmax(A_sp @ S2), 4-edge wide gather
    spmm_softmax_k<<<NN / 4, 256, 0, stream>>>(rowptr, esw, S2, out);
}